// Round 2
// baseline (1853.068 us; speedup 1.0000x reference)
//
#include <hip/hip_runtime.h>

#define G   160
#define G3  (G*G*G)          // 4,096,000
#define NV  300000
#define EPS 1e-4f
#define CAP 32768            // per-offset pair capacity (expected ~22k, +75 sigma)

typedef unsigned short u16;
typedef __attribute__((ext_vector_type(8))) short bf16x8;
typedef __attribute__((ext_vector_type(4))) float f32x4;

// ---- workspace layout (bytes) ----
// outh (N x 128 fp32 conv1 accumulator). The voxel hash grid overlays its first
// 16.4 MB (dead before conv1_self writes), and bf16 h1 overlays it in place after bn2.
#define OFF_OUTH 0ull
#define OFF_PIN  153600000ull                    // 27*CAP*4
#define OFF_POUT (OFF_PIN  + 3538944ull)
#define OFF_CNT  (OFF_POUT + 3538944ull)         // 128 B
#define OFF_H0   (OFF_CNT  + 128ull)             // N*64*2 bf16
#define OFF_W1T  (OFF_H0   + 38400000ull)        // 27*128*64*2  (B^T layout [k][cout][cin])
#define OFF_W2T  (OFF_W1T  + 442368ull)          // 27*128*128*2
#define OFF_LINW (OFF_W2T  + 884736ull)          // 128*64*2
#define WS_NEED  (OFF_LINW + 16384ull)           // ~200.4 MB

__device__ __forceinline__ u16 f2bf(float f) {   // fp32 -> bf16 RNE
  unsigned u = __float_as_uint(f);
  return (u16)((u + 0x7fffu + ((u >> 16) & 1u)) >> 16);
}

// ---------- phase 1: hash grid + pair lists ----------
__global__ void k_grid(const int* __restrict__ pos, int* __restrict__ grid) {
  int i = blockIdx.x * 256 + threadIdx.x;
  if (i < NV)
    grid[(pos[3*i] * G + pos[3*i+1]) * G + pos[3*i+2]] = i;
}

// R1: barrier-free rewrite. 26 grid lookups issued back-to-back (pipelined),
// then wave-ballot compaction with 26 independent global atomics.
// Old version: 3 __syncthreads x 26 iters serialized one lookup at a time -> 343 us.
__global__ __launch_bounds__(256) void k_pairs(const int* __restrict__ pos,
                        const int* __restrict__ grid,
                        int* __restrict__ pin, int* __restrict__ pout,
                        int* __restrict__ counts) {
  int t = threadIdx.x, lane = t & 63;
  int i = blockIdx.x * 256 + t;
  bool act = (i < NV);
  int p0 = 0, p1 = 1 << 20, p2 = 0;              // inactive threads -> always OOB
  if (act) { p0 = pos[3*i]; p1 = pos[3*i+1]; p2 = pos[3*i+2]; }

  int j[26];
  #pragma unroll
  for (int kk = 0; kk < 26; kk++) {              // all loads independent & in flight
    int k = kk < 13 ? kk : kk + 1;
    int q0 = p0 + k/9 - 1, q1 = p1 + (k/3)%3 - 1, q2 = p2 + k%3 - 1;
    bool inb = (q0 >= 0 && q0 < G && q1 >= 0 && q1 < G && q2 >= 0 && q2 < G);
    int addr = inb ? (q0*G + q1)*G + q2 : 0;     // clamped: unconditional load, no divergence
    int jj = grid[addr];
    j[kk] = inb ? jj : -1;
  }

  unsigned long long m[26];
  #pragma unroll
  for (int kk = 0; kk < 26; kk++) m[kk] = __ballot(j[kk] >= 0);

  int base[26];
  #pragma unroll
  for (int kk = 0; kk < 26; kk++) {              // 26 independent atomics, pipelined
    int k = kk < 13 ? kk : kk + 1;
    int b = 0;
    if (lane == 0) b = atomicAdd(&counts[k], (int)__popcll(m[kk]));
    base[kk] = b;
  }

  #pragma unroll
  for (int kk = 0; kk < 26; kk++) {
    int b = __shfl(base[kk], 0);
    if (j[kk] >= 0) {
      int k = kk < 13 ? kk : kk + 1;
      int slot = b + (int)__popcll(m[kk] & ((1ull << lane) - 1ull));
      if (slot < CAP) { pin[k*CAP + slot] = j[kk]; pout[k*CAP + slot] = i; }
    }
  }
}

// ---------- phase 2: BN1+ReLU -> bf16 h0 ; weight cast/transpose ----------
__global__ void k_bn1(const float* __restrict__ feat, const float* g, const float* b,
                      const float* m, const float* v, u16* __restrict__ h0) {
  __shared__ float ss[64], tt[64];
  int t = threadIdx.x;
  if (t < 64) { float s = g[t] * rsqrtf(v[t] + EPS); ss[t] = s; tt[t] = b[t] - m[t]*s; }
  __syncthreads();
  long gt = (long)blockIdx.x * 256 + t;            // one thread per 4 elems
  if (gt >= (long)NV * 16) return;
  int c = (int)(gt & 15) * 4;
  float4 x = ((const float4*)feat)[gt];
  ushort4 q;
  q.x = f2bf(fmaxf(x.x*ss[c  ] + tt[c  ], 0.f));
  q.y = f2bf(fmaxf(x.y*ss[c+1] + tt[c+1], 0.f));
  q.z = f2bf(fmaxf(x.z*ss[c+2] + tt[c+2], 0.f));
  q.w = f2bf(fmaxf(x.w*ss[c+3] + tt[c+3], 0.f));
  ((ushort4*)h0)[gt] = q;
}

// W -> bf16, transposed to [k][cout][cin] so MFMA B-frags are k-contiguous.
__global__ void k_weights(const float* __restrict__ W1, const float* __restrict__ W2,
                          const float* __restrict__ linw,
                          u16* __restrict__ w1t, u16* __restrict__ w2t, u16* __restrict__ lwt) {
  __shared__ float tmp[8192];
  int b = blockIdx.x, t = threadIdx.x;
  if (b < 27) {                                    // W1[k]: [64][128] -> [128][64]
    const float* src = W1 + b * 8192;
    u16* dst = w1t + b * 8192;
    for (int u = t; u < 8192; u += 256) tmp[u] = src[u];
    __syncthreads();
    for (int u = t; u < 8192; u += 256) { int c = u >> 6, a = u & 63; dst[c*64 + a] = f2bf(tmp[a*128 + c]); }
  } else if (b < 54) {                             // W2[k]: [128][128] -> [128][128]^T, two halves
    int k = b - 27;
    const float* src = W2 + k * 16384;
    u16* dst = w2t + k * 16384;
    for (int h = 0; h < 2; h++) {
      for (int u = t; u < 8192; u += 256) tmp[u] = src[h*8192 + u];
      __syncthreads();
      for (int u = t; u < 8192; u += 256) { int c = u >> 6, a = u & 63; dst[c*128 + h*64 + a] = f2bf(tmp[a*128 + c]); }
      __syncthreads();
    }
  } else {                                         // lin_w [128][64] is already B^T layout
    for (int u = t; u < 8192; u += 256) lwt[u] = f2bf(linw[u]);
  }
}

// ---------- GEMM building blocks (128 rows x 128 cols tile, 4 waves, 64x64 quadrants) ----------
template<int K, int RS>   // K: reduce dim; RS: global row stride (bf16 elems)
__device__ __forceinline__ void stage_rows(const u16* __restrict__ src, const int* sidx, u16* lds) {
  const int LPR = K / 8, RPI = 256 / LPR;          // 16B loaders per row, rows per iter
  int t = threadIdx.x, o = t % LPR, r0 = t / LPR;
  #pragma unroll
  for (int r = r0; r < 128; r += RPI) {
    int j = sidx[r];
    int4 val = make_int4(0, 0, 0, 0);
    if (j >= 0) val = *(const int4*)(src + (long)j * RS + o * 8);
    *(int4*)(lds + r * (K + 8) + o * 8) = val;     // +8 elem pad: 2-way-max LDS banking
  }
}

__device__ __forceinline__ void stage_feat(const float* __restrict__ feat, int row0, u16* lds) {
  int t = threadIdx.x, o = t & 15, r0 = t >> 4;    // fp32->bf16 on the fly, K=64
  #pragma unroll
  for (int r = r0; r < 128; r += 16) {
    int row = row0 + r;
    float4 x = make_float4(0.f, 0.f, 0.f, 0.f);
    if (row < NV) x = *(const float4*)(feat + (long)row * 64 + o * 4);
    ushort4 q; q.x = f2bf(x.x); q.y = f2bf(x.y); q.z = f2bf(x.z); q.w = f2bf(x.w);
    *(ushort4*)(lds + r * 72 + o * 4) = q;
  }
}

template<int K>           // A from padded LDS; B-frags straight from L2-hot transposed weights
__device__ __forceinline__ void mma_tile(const u16* As, const u16* __restrict__ wt, f32x4 acc[4][4]) {
  int lane = threadIdx.x & 63, wave = threadIdx.x >> 6;
  int wr = (wave >> 1) * 64, wc = (wave & 1) * 64;
  int lr = lane & 15, lk = (lane >> 4) * 8;
  #pragma unroll
  for (int kk = 0; kk < K; kk += 32) {
    bf16x8 a[4], b[4];
    #pragma unroll
    for (int f = 0; f < 4; f++) a[f] = *(const bf16x8*)(As + (wr + f*16 + lr) * (K + 8) + kk + lk);
    #pragma unroll
    for (int f = 0; f < 4; f++) b[f] = *(const bf16x8*)(wt + (wc + f*16 + lr) * K + kk + lk);
    #pragma unroll
    for (int fr = 0; fr < 4; fr++)
      #pragma unroll
      for (int fc = 0; fc < 4; fc++)
        acc[fr][fc] = __builtin_amdgcn_mfma_f32_16x16x32_bf16(a[fr], b[fc], acc[fr][fc], 0, 0, 0);
  }
}

// ---------- conv1 self tap: outh = h0 @ W1[13] (initializes full accumulator) ----------
__global__ __launch_bounds__(256) void k_conv1_self(const u16* __restrict__ h0,
                                                    const u16* __restrict__ w1t,
                                                    float* __restrict__ outh) {
  __shared__ u16 As[128 * 72];
  __shared__ int sidx[128];
  int t = threadIdx.x, row0 = blockIdx.x * 128;
  if (t < 128) sidx[t] = (row0 + t < NV) ? row0 + t : -1;
  __syncthreads();
  stage_rows<64, 64>(h0, sidx, As);
  __syncthreads();
  f32x4 acc[4][4] = {};
  mma_tile<64>(As, w1t + 13 * 8192, acc);
  int lane = t & 63, wave = t >> 6;
  int wr = (wave >> 1) * 64, wc = (wave & 1) * 64, cr = (lane >> 4) * 4, cc = lane & 15;
  #pragma unroll
  for (int fr = 0; fr < 4; fr++)
    #pragma unroll
    for (int r = 0; r < 4; r++) {
      int row = row0 + wr + fr*16 + cr + r;
      if (row >= NV) continue;
      #pragma unroll
      for (int fc = 0; fc < 4; fc++)
        outh[(long)row * 128 + wc + fc*16 + cc] = acc[fr][fc][r];
    }
}

// ---------- non-self taps: gather-GEMM + fp32 atomic scatter-add ----------
template<int K, int RS>
__global__ __launch_bounds__(256) void k_conv_scat(const u16* __restrict__ h, const u16* __restrict__ wt,
                                                   const int* __restrict__ pin, const int* __restrict__ pout,
                                                   const int* __restrict__ counts, float* __restrict__ dst) {
  int k = blockIdx.y;
  int cnt = counts[k]; if (cnt > CAP) cnt = CAP;
  int base = blockIdx.x * 128;
  if (base >= cnt) return;                          // k==13 (cnt 0) and tail tiles exit here
  __shared__ u16 As[128 * (K + 8)];
  __shared__ int sin[128], sout[128];
  int t = threadIdx.x;
  if (t < 128) sin[t] = (base + t < cnt) ? pin[k*CAP + base + t] : -1;
  else         sout[t - 128] = (base + t - 128 < cnt) ? pout[k*CAP + base + t - 128] : -1;
  __syncthreads();
  stage_rows<K, RS>(h, sin, As);
  __syncthreads();
  f32x4 acc[4][4] = {};
  mma_tile<K>(As, wt + k * (K * 128), acc);
  int lane = t & 63, wave = t >> 6;
  int wr = (wave >> 1) * 64, wc = (wave & 1) * 64, cr = (lane >> 4) * 4, cc = lane & 15;
  #pragma unroll
  for (int fr = 0; fr < 4; fr++)
    #pragma unroll
    for (int r = 0; r < 4; r++) {
      int orow = sout[wr + fr*16 + cr + r];
      if (orow < 0) continue;
      #pragma unroll
      for (int fc = 0; fc < 4; fc++)
        unsafeAtomicAdd(&dst[(long)orow * 128 + wc + fc*16 + cc], acc[fr][fc][r]);
    }
}

// ---------- BN2+ReLU, bf16 h1 written in place over outh (row stride 512 B) ----------
__global__ void k_bn2(float* __restrict__ outh, const float* g, const float* b,
                      const float* m, const float* v) {
  __shared__ float ss[128], tt[128];
  int t = threadIdx.x;
  if (t < 128) { float s = g[t] * rsqrtf(v[t] + EPS); ss[t] = s; tt[t] = b[t] - m[t]*s; }
  __syncthreads();
  int w = blockIdx.x * 4 + (t >> 6);                // one wave per row; loads precede stores in wave order
  int lane = t & 63;
  if (w >= NV) return;
  int c = lane * 2;
  float2 x = *(float2*)(outh + (long)w * 128 + c);
  ushort2 q;
  q.x = f2bf(fmaxf(x.x * ss[c  ] + tt[c  ], 0.f));
  q.y = f2bf(fmaxf(x.y * ss[c+1] + tt[c+1], 0.f));
  *(ushort2*)((char*)outh + (size_t)w * 512 + lane * 4) = q;
}

// ---------- conv2 self tap + NiN skip: out = feat@lin_w^T + h1@W2[13] ----------
__global__ __launch_bounds__(256) void k_conv2_self(const float* __restrict__ feat,
                                                    const u16* __restrict__ lwt,
                                                    const u16* __restrict__ h1,
                                                    const u16* __restrict__ w2t,
                                                    float* __restrict__ out) {
  __shared__ u16 As[128 * 136];
  __shared__ int sidx[128];
  int t = threadIdx.x, row0 = blockIdx.x * 128;
  if (t < 128) sidx[t] = (row0 + t < NV) ? row0 + t : -1;
  __syncthreads();
  f32x4 acc[4][4] = {};
  stage_feat(feat, row0, As);                       // K=64 segment (stride 72 region)
  __syncthreads();
  mma_tile<64>(As, lwt, acc);
  __syncthreads();
  stage_rows<128, 256>(h1, sidx, As);               // K=128 segment (h1 row stride 256 elems)
  __syncthreads();
  mma_tile<128>(As, w2t + 13 * 16384, acc);
  int lane = t & 63, wave = t >> 6;
  int wr = (wave >> 1) * 64, wc = (wave & 1) * 64, cr = (lane >> 4) * 4, cc = lane & 15;
  #pragma unroll
  for (int fr = 0; fr < 4; fr++)
    #pragma unroll
    for (int r = 0; r < 4; r++) {
      int row = row0 + wr + fr*16 + cr + r;
      if (row >= NV) continue;
      #pragma unroll
      for (int fc = 0; fc < 4; fc++)
        out[(long)row * 128 + wc + fc*16 + cc] = acc[fr][fc][r];
    }
}

extern "C" void kernel_launch(void* const* d_in, const int* in_sizes, int n_in,
                              void* d_out, int out_size, void* d_ws, size_t ws_size,
                              hipStream_t stream) {
  const float* feat = (const float*)d_in[0];
  const int*   pos  = (const int*)d_in[1];
  const float* linw = (const float*)d_in[2];
  const float* g1 = (const float*)d_in[3], *b1 = (const float*)d_in[4];
  const float* m1 = (const float*)d_in[5], *v1 = (const float*)d_in[6];
  const float* W1 = (const float*)d_in[7];
  const float* g2 = (const float*)d_in[8], *b2 = (const float*)d_in[9];
  const float* m2 = (const float*)d_in[10], *v2 = (const float*)d_in[11];
  const float* W2 = (const float*)d_in[12];

  if (ws_size < WS_NEED) return;  // insufficient scratch; fail visibly rather than corrupt

  char* ws = (char*)d_ws;
  int*   grid   = (int*)(ws + OFF_OUTH);            // overlays outh, dead before conv1_self
  float* outh   = (float*)(ws + OFF_OUTH);
  int*   pin    = (int*)(ws + OFF_PIN);
  int*   pout   = (int*)(ws + OFF_POUT);
  int*   counts = (int*)(ws + OFF_CNT);
  u16*   h0     = (u16*)(ws + OFF_H0);
  u16*   w1t    = (u16*)(ws + OFF_W1T);
  u16*   w2t    = (u16*)(ws + OFF_W2T);
  u16*   lwt    = (u16*)(ws + OFF_LINW);
  float* out    = (float*)d_out;

  hipMemsetAsync(grid, 0xFF, (size_t)G3 * 4, stream);       // grid = -1
  hipMemsetAsync(counts, 0, 128, stream);

  k_grid  <<<(NV + 255) / 256, 256, 0, stream>>>(pos, grid);
  k_pairs <<<(NV + 255) / 256, 256, 0, stream>>>(pos, grid, pin, pout, counts);
  k_bn1   <<<(NV * 16) / 256, 256, 0, stream>>>(feat, g1, b1, m1, v1, h0);
  k_weights<<<55, 256, 0, stream>>>(W1, W2, linw, w1t, w2t, lwt);

  dim3 gself((NV + 127) / 128);
  dim3 gscat(CAP / 128, 27);
  k_conv1_self<<<gself, 256, 0, stream>>>(h0, w1t, outh);
  k_conv_scat<64, 64><<<gscat, 256, 0, stream>>>(h0, w1t, pin, pout, counts, outh);
  k_bn2<<<NV / 4, 256, 0, stream>>>(outh, g2, b2, m2, v2);
  k_conv2_self<<<gself, 256, 0, stream>>>(feat, lwt, (const u16*)outh, w2t, out);
  k_conv_scat<128, 256><<<gscat, 256, 0, stream>>>((const u16*)outh, w2t, pin, pout, counts, out);
}

// Round 3
// 914.483 us; speedup vs baseline: 2.0264x; 2.0264x over previous
//
#include <hip/hip_runtime.h>

#define G   160
#define G3  (G*G*G)          // 4,096,000
#define NV  300000
#define EPS 1e-4f
#define CAP 32768            // per-offset pair capacity (expected ~22k, +75 sigma)
#define CPAD 32              // counts[k] lives at counts[k*CPAD]: one 128B line per counter

typedef unsigned short u16;
typedef __attribute__((ext_vector_type(8))) short bf16x8;
typedef __attribute__((ext_vector_type(4))) float f32x4;

// ---- workspace layout (bytes) ----
#define OFF_OUTH 0ull
#define OFF_PIN  153600000ull                    // outh = 300000*128*4
#define OFF_POUT (OFF_PIN  + 3538944ull)         // 27*CAP*4
#define OFF_CNT  (OFF_POUT + 3538944ull)
#define OFF_H0   (OFF_CNT  + 4096ull)            // padded counters (27*128 B)
#define OFF_W1T  (OFF_H0   + 38400000ull)        // N*64*2 bf16
#define OFF_W2T  (OFF_W1T  + 442368ull)          // 27*128*64*2  (B^T layout [k][cout][cin])
#define OFF_LINW (OFF_W2T  + 884736ull)          // 27*128*128*2
#define WS_NEED  (OFF_LINW + 16384ull)           // ~200.4 MB

__device__ __forceinline__ u16 f2bf(float f) {   // fp32 -> bf16 RNE
  unsigned u = __float_as_uint(f);
  return (u16)((u + 0x7fffu + ((u >> 16) & 1u)) >> 16);
}

// ---------- phase 1: hash grid + pair lists ----------
__global__ void k_grid(const int* __restrict__ pos, int* __restrict__ grid) {
  int i = blockIdx.x * 256 + threadIdx.x;
  if (i < NV)
    grid[(pos[3*i] * G + pos[3*i+1]) * G + pos[3*i+2]] = i;
}

// R2 post-mortem: contested same-cache-line atomics serialize at L2 (~17cy each).
// R0: 30k/line -> 343us. R1: 122k/line -> 1011us. Fix: LDS-hierarchical (back to
// 1 global atomic per block per k) AND pad each counter to its own 128B line.
// Keep R1's pipelined 26-deep lookup burst.
__global__ __launch_bounds__(256) void k_pairs(const int* __restrict__ pos,
                        const int* __restrict__ grid,
                        int* __restrict__ pin, int* __restrict__ pout,
                        int* __restrict__ counts) {
  __shared__ int lcnt[27];
  __shared__ int wboff[27][4];
  __shared__ int gbase[27];
  int t = threadIdx.x, lane = t & 63, wv = t >> 6;
  if (t < 27) lcnt[t] = 0;
  int i = blockIdx.x * 256 + t;
  bool act = (i < NV);
  int p0 = 0, p1 = 1 << 20, p2 = 0;              // inactive threads -> always OOB
  if (act) { p0 = pos[3*i]; p1 = pos[3*i+1]; p2 = pos[3*i+2]; }
  __syncthreads();                               // lcnt zeroed

  int j[26];
  #pragma unroll
  for (int kk = 0; kk < 26; kk++) {              // all 26 loads independent & in flight
    int k = kk < 13 ? kk : kk + 1;
    int q0 = p0 + k/9 - 1, q1 = p1 + (k/3)%3 - 1, q2 = p2 + k%3 - 1;
    bool inb = (q0 >= 0 && q0 < G && q1 >= 0 && q1 < G && q2 >= 0 && q2 < G);
    int addr = inb ? (q0*G + q1)*G + q2 : 0;     // clamped: unconditional load
    int jj = grid[addr];
    j[kk] = inb ? jj : -1;
  }

  unsigned long long m[26];                      // wave-uniform -> SGPRs
  #pragma unroll
  for (int kk = 0; kk < 26; kk++) m[kk] = __ballot(j[kk] >= 0);

  #pragma unroll
  for (int kk = 0; kk < 26; kk++) {              // per-block aggregation in LDS
    int k = kk < 13 ? kk : kk + 1;
    if (lane == 0) wboff[k][wv] = atomicAdd(&lcnt[k], (int)__popcll(m[kk]));
  }
  __syncthreads();
  if (t < 27 && t != 13)                         // 27 concurrent atomics, separate L2 lines
    gbase[t] = atomicAdd(&counts[t * CPAD], lcnt[t]);
  __syncthreads();

  #pragma unroll
  for (int kk = 0; kk < 26; kk++) {
    if (j[kk] >= 0) {
      int k = kk < 13 ? kk : kk + 1;
      int slot = gbase[k] + wboff[k][wv] + (int)__popcll(m[kk] & ((1ull << lane) - 1ull));
      if (slot < CAP) { pin[k*CAP + slot] = j[kk]; pout[k*CAP + slot] = i; }
    }
  }
}

// ---------- phase 2: BN1+ReLU -> bf16 h0 ; weight cast/transpose ----------
__global__ void k_bn1(const float* __restrict__ feat, const float* g, const float* b,
                      const float* m, const float* v, u16* __restrict__ h0) {
  __shared__ float ss[64], tt[64];
  int t = threadIdx.x;
  if (t < 64) { float s = g[t] * rsqrtf(v[t] + EPS); ss[t] = s; tt[t] = b[t] - m[t]*s; }
  __syncthreads();
  long gt = (long)blockIdx.x * 256 + t;            // one thread per 4 elems
  if (gt >= (long)NV * 16) return;
  int c = (int)(gt & 15) * 4;
  float4 x = ((const float4*)feat)[gt];
  ushort4 q;
  q.x = f2bf(fmaxf(x.x*ss[c  ] + tt[c  ], 0.f));
  q.y = f2bf(fmaxf(x.y*ss[c+1] + tt[c+1], 0.f));
  q.z = f2bf(fmaxf(x.z*ss[c+2] + tt[c+2], 0.f));
  q.w = f2bf(fmaxf(x.w*ss[c+3] + tt[c+3], 0.f));
  ((ushort4*)h0)[gt] = q;
}

// W -> bf16, transposed to [k][cout][cin] so MFMA B-frags are k-contiguous.
__global__ void k_weights(const float* __restrict__ W1, const float* __restrict__ W2,
                          const float* __restrict__ linw,
                          u16* __restrict__ w1t, u16* __restrict__ w2t, u16* __restrict__ lwt) {
  __shared__ float tmp[8192];
  int b = blockIdx.x, t = threadIdx.x;
  if (b < 27) {                                    // W1[k]: [64][128] -> [128][64]
    const float* src = W1 + b * 8192;
    u16* dst = w1t + b * 8192;
    for (int u = t; u < 8192; u += 256) tmp[u] = src[u];
    __syncthreads();
    for (int u = t; u < 8192; u += 256) { int c = u >> 6, a = u & 63; dst[c*64 + a] = f2bf(tmp[a*128 + c]); }
  } else if (b < 54) {                             // W2[k]: [128][128] -> [128][128]^T, two halves
    int k = b - 27;
    const float* src = W2 + k * 16384;
    u16* dst = w2t + k * 16384;
    for (int h = 0; h < 2; h++) {
      for (int u = t; u < 8192; u += 256) tmp[u] = src[h*8192 + u];
      __syncthreads();
      for (int u = t; u < 8192; u += 256) { int c = u >> 6, a = u & 63; dst[c*128 + h*64 + a] = f2bf(tmp[a*128 + c]); }
      __syncthreads();
    }
  } else {                                         // lin_w [128][64] is already B^T layout
    for (int u = t; u < 8192; u += 256) lwt[u] = f2bf(linw[u]);
  }
}

// ---------- GEMM building blocks (128 rows x 128 cols tile, 4 waves, 64x64 quadrants) ----------
template<int K, int RS>   // K: reduce dim; RS: global row stride (bf16 elems)
__device__ __forceinline__ void stage_rows(const u16* __restrict__ src, const int* sidx, u16* lds) {
  const int LPR = K / 8, RPI = 256 / LPR;          // 16B loaders per row, rows per iter
  int t = threadIdx.x, o = t % LPR, r0 = t / LPR;
  #pragma unroll
  for (int r = r0; r < 128; r += RPI) {
    int j = sidx[r];
    int4 val = make_int4(0, 0, 0, 0);
    if (j >= 0) val = *(const int4*)(src + (long)j * RS + o * 8);
    *(int4*)(lds + r * (K + 8) + o * 8) = val;     // +8 elem pad: 2-way-max LDS banking
  }
}

__device__ __forceinline__ void stage_feat(const float* __restrict__ feat, int row0, u16* lds) {
  int t = threadIdx.x, o = t & 15, r0 = t >> 4;    // fp32->bf16 on the fly, K=64
  #pragma unroll
  for (int r = r0; r < 128; r += 16) {
    int row = row0 + r;
    float4 x = make_float4(0.f, 0.f, 0.f, 0.f);
    if (row < NV) x = *(const float4*)(feat + (long)row * 64 + o * 4);
    ushort4 q; q.x = f2bf(x.x); q.y = f2bf(x.y); q.z = f2bf(x.z); q.w = f2bf(x.w);
    *(ushort4*)(lds + r * 72 + o * 4) = q;
  }
}

template<int K>           // A from padded LDS; B-frags straight from L2-hot transposed weights
__device__ __forceinline__ void mma_tile(const u16* As, const u16* __restrict__ wt, f32x4 acc[4][4]) {
  int lane = threadIdx.x & 63, wave = threadIdx.x >> 6;
  int wr = (wave >> 1) * 64, wc = (wave & 1) * 64;
  int lr = lane & 15, lk = (lane >> 4) * 8;
  #pragma unroll
  for (int kk = 0; kk < K; kk += 32) {
    bf16x8 a[4], b[4];
    #pragma unroll
    for (int f = 0; f < 4; f++) a[f] = *(const bf16x8*)(As + (wr + f*16 + lr) * (K + 8) + kk + lk);
    #pragma unroll
    for (int f = 0; f < 4; f++) b[f] = *(const bf16x8*)(wt + (wc + f*16 + lr) * K + kk + lk);
    #pragma unroll
    for (int fr = 0; fr < 4; fr++)
      #pragma unroll
      for (int fc = 0; fc < 4; fc++)
        acc[fr][fc] = __builtin_amdgcn_mfma_f32_16x16x32_bf16(a[fr], b[fc], acc[fr][fc], 0, 0, 0);
  }
}

// ---------- conv1 self tap: outh = h0 @ W1[13] (initializes full accumulator) ----------
__global__ __launch_bounds__(256) void k_conv1_self(const u16* __restrict__ h0,
                                                    const u16* __restrict__ w1t,
                                                    float* __restrict__ outh) {
  __shared__ u16 As[128 * 72];
  __shared__ int sidx[128];
  int t = threadIdx.x, row0 = blockIdx.x * 128;
  if (t < 128) sidx[t] = (row0 + t < NV) ? row0 + t : -1;
  __syncthreads();
  stage_rows<64, 64>(h0, sidx, As);
  __syncthreads();
  f32x4 acc[4][4] = {};
  mma_tile<64>(As, w1t + 13 * 8192, acc);
  int lane = t & 63, wave = t >> 6;
  int wr = (wave >> 1) * 64, wc = (wave & 1) * 64, cr = (lane >> 4) * 4, cc = lane & 15;
  #pragma unroll
  for (int fr = 0; fr < 4; fr++)
    #pragma unroll
    for (int r = 0; r < 4; r++) {
      int row = row0 + wr + fr*16 + cr + r;
      if (row >= NV) continue;
      #pragma unroll
      for (int fc = 0; fc < 4; fc++)
        outh[(long)row * 128 + wc + fc*16 + cc] = acc[fr][fc][r];
    }
}

// ---------- non-self taps: gather-GEMM + fp32 atomic scatter-add ----------
template<int K, int RS>
__global__ __launch_bounds__(256) void k_conv_scat(const u16* __restrict__ h, const u16* __restrict__ wt,
                                                   const int* __restrict__ pin, const int* __restrict__ pout,
                                                   const int* __restrict__ counts, float* __restrict__ dst) {
  int k = blockIdx.y;
  int cnt = counts[k * CPAD]; if (cnt > CAP) cnt = CAP;
  int base = blockIdx.x * 128;
  if (base >= cnt) return;                          // k==13 (cnt 0) and tail tiles exit here
  __shared__ u16 As[128 * (K + 8)];
  __shared__ int sin[128], sout[128];
  int t = threadIdx.x;
  if (t < 128) sin[t] = (base + t < cnt) ? pin[k*CAP + base + t] : -1;
  else         sout[t - 128] = (base + t - 128 < cnt) ? pout[k*CAP + base + t - 128] : -1;
  __syncthreads();
  stage_rows<K, RS>(h, sin, As);
  __syncthreads();
  f32x4 acc[4][4] = {};
  mma_tile<K>(As, wt + k * (K * 128), acc);
  int lane = t & 63, wave = t >> 6;
  int wr = (wave >> 1) * 64, wc = (wave & 1) * 64, cr = (lane >> 4) * 4, cc = lane & 15;
  #pragma unroll
  for (int fr = 0; fr < 4; fr++)
    #pragma unroll
    for (int r = 0; r < 4; r++) {
      int orow = sout[wr + fr*16 + cr + r];
      if (orow < 0) continue;
      #pragma unroll
      for (int fc = 0; fc < 4; fc++)
        unsafeAtomicAdd(&dst[(long)orow * 128 + wc + fc*16 + cc], acc[fr][fc][r]);
    }
}

// ---------- BN2+ReLU, bf16 h1 written in place over outh (row stride 512 B) ----------
__global__ void k_bn2(float* __restrict__ outh, const float* g, const float* b,
                      const float* m, const float* v) {
  __shared__ float ss[128], tt[128];
  int t = threadIdx.x;
  if (t < 128) { float s = g[t] * rsqrtf(v[t] + EPS); ss[t] = s; tt[t] = b[t] - m[t]*s; }
  __syncthreads();
  int w = blockIdx.x * 4 + (t >> 6);                // one wave per row; loads precede stores in wave order
  int lane = t & 63;
  if (w >= NV) return;
  int c = lane * 2;
  float2 x = *(float2*)(outh + (long)w * 128 + c);
  ushort2 q;
  q.x = f2bf(fmaxf(x.x * ss[c  ] + tt[c  ], 0.f));
  q.y = f2bf(fmaxf(x.y * ss[c+1] + tt[c+1], 0.f));
  *(ushort2*)((char*)outh + (size_t)w * 512 + lane * 4) = q;
}

// ---------- conv2 self tap + NiN skip: out = feat@lin_w^T + h1@W2[13] ----------
__global__ __launch_bounds__(256) void k_conv2_self(const float* __restrict__ feat,
                                                    const u16* __restrict__ lwt,
                                                    const u16* __restrict__ h1,
                                                    const u16* __restrict__ w2t,
                                                    float* __restrict__ out) {
  __shared__ u16 As[128 * 136];
  __shared__ int sidx[128];
  int t = threadIdx.x, row0 = blockIdx.x * 128;
  if (t < 128) sidx[t] = (row0 + t < NV) ? row0 + t : -1;
  __syncthreads();
  f32x4 acc[4][4] = {};
  stage_feat(feat, row0, As);                       // K=64 segment (stride 72 region)
  __syncthreads();
  mma_tile<64>(As, lwt, acc);
  __syncthreads();
  stage_rows<128, 256>(h1, sidx, As);               // K=128 segment (h1 row stride 256 elems)
  __syncthreads();
  mma_tile<128>(As, w2t + 13 * 16384, acc);
  int lane = t & 63, wave = t >> 6;
  int wr = (wave >> 1) * 64, wc = (wave & 1) * 64, cr = (lane >> 4) * 4, cc = lane & 15;
  #pragma unroll
  for (int fr = 0; fr < 4; fr++)
    #pragma unroll
    for (int r = 0; r < 4; r++) {
      int row = row0 + wr + fr*16 + cr + r;
      if (row >= NV) continue;
      #pragma unroll
      for (int fc = 0; fc < 4; fc++)
        out[(long)row * 128 + wc + fc*16 + cc] = acc[fr][fc][r];
    }
}

extern "C" void kernel_launch(void* const* d_in, const int* in_sizes, int n_in,
                              void* d_out, int out_size, void* d_ws, size_t ws_size,
                              hipStream_t stream) {
  const float* feat = (const float*)d_in[0];
  const int*   pos  = (const int*)d_in[1];
  const float* linw = (const float*)d_in[2];
  const float* g1 = (const float*)d_in[3], *b1 = (const float*)d_in[4];
  const float* m1 = (const float*)d_in[5], *v1 = (const float*)d_in[6];
  const float* W1 = (const float*)d_in[7];
  const float* g2 = (const float*)d_in[8], *b2 = (const float*)d_in[9];
  const float* m2 = (const float*)d_in[10], *v2 = (const float*)d_in[11];
  const float* W2 = (const float*)d_in[12];

  if (ws_size < WS_NEED) return;  // insufficient scratch; fail visibly rather than corrupt

  char* ws = (char*)d_ws;
  int*   grid   = (int*)(ws + OFF_OUTH);            // overlays outh, dead before conv1_self
  float* outh   = (float*)(ws + OFF_OUTH);
  int*   pin    = (int*)(ws + OFF_PIN);
  int*   pout   = (int*)(ws + OFF_POUT);
  int*   counts = (int*)(ws + OFF_CNT);
  u16*   h0     = (u16*)(ws + OFF_H0);
  u16*   w1t    = (u16*)(ws + OFF_W1T);
  u16*   w2t    = (u16*)(ws + OFF_W2T);
  u16*   lwt    = (u16*)(ws + OFF_LINW);
  float* out    = (float*)d_out;

  hipMemsetAsync(grid, 0xFF, (size_t)G3 * 4, stream);       // grid = -1
  hipMemsetAsync(counts, 0, 27 * CPAD * 4, stream);

  k_grid  <<<(NV + 255) / 256, 256, 0, stream>>>(pos, grid);
  k_pairs <<<(NV + 255) / 256, 256, 0, stream>>>(pos, grid, pin, pout, counts);
  k_bn1   <<<(NV * 16) / 256, 256, 0, stream>>>(feat, g1, b1, m1, v1, h0);
  k_weights<<<55, 256, 0, stream>>>(W1, W2, linw, w1t, w2t, lwt);

  dim3 gself((NV + 127) / 128);
  dim3 gscat(CAP / 128, 27);
  k_conv1_self<<<gself, 256, 0, stream>>>(h0, w1t, outh);
  k_conv_scat<64, 64><<<gscat, 256, 0, stream>>>(h0, w1t, pin, pout, counts, outh);
  k_bn2<<<NV / 4, 256, 0, stream>>>(outh, g2, b2, m2, v2);
  k_conv2_self<<<gself, 256, 0, stream>>>(feat, lwt, (const u16*)outh, w2t, out);
  k_conv_scat<128, 256><<<gscat, 256, 0, stream>>>((const u16*)outh, w2t, pin, pout, counts, out);
}